// Round 1
// baseline (127.431 us; speedup 1.0000x reference)
//
#include <hip/hip_runtime.h>
#include <math.h>

#define Bn 48
#define Ln 17
#define Dn 256
#define Mn 768        // Bn*(Ln-1)
#define ROWS 816      // Bn*Ln rows: 48 anchors + 768 toks
#define NEGV -1000000000.0

// ---------- block reductions (blockDim.x multiple of 64) ----------
static __device__ __forceinline__ double blockReduceSum(double v, double* sdata) {
  #pragma unroll
  for (int o = 32; o > 0; o >>= 1) v += __shfl_down(v, o, 64);
  int lane = threadIdx.x & 63, wid = threadIdx.x >> 6;
  __syncthreads();
  if (lane == 0) sdata[wid] = v;
  __syncthreads();
  int nw = blockDim.x >> 6;
  double r = sdata[0];
  for (int w = 1; w < nw; ++w) r += sdata[w];
  return r;
}

static __device__ __forceinline__ double blockReduceMax(double v, double* sdata) {
  #pragma unroll
  for (int o = 32; o > 0; o >>= 1) v = fmax(v, __shfl_down(v, o, 64));
  int lane = threadIdx.x & 63, wid = threadIdx.x >> 6;
  __syncthreads();
  if (lane == 0) sdata[wid] = v;
  __syncthreads();
  int nw = blockDim.x >> 6;
  double r = sdata[0];
  for (int w = 1; w < nw; ++w) r = fmax(r, sdata[w]);
  return r;
}

// ---------- K1: normalize rows of x; write [anchors(48); toks(768)] fp32 ----------
__global__ __launch_bounds__(256) void k1_normalize(const float* __restrict__ x,
                                                    float* __restrict__ xn) {
  __shared__ double red[8];
  int row = blockIdx.x;            // 0..815 over (b,l)
  int b = row / Ln, l = row % Ln;
  int tid = threadIdx.x;
  float v = x[row * Dn + tid];
  double ss = blockReduceSum((double)v * (double)v, red);
  double norm = sqrt(ss);
  double denom = fmax(norm, 1e-12);
  float o = (float)((double)v / denom);
  int orow = (l == 0) ? b : (Bn + b * (Ln - 1) + (l - 1));
  xn[orow * Dn + tid] = o;
}

// ---------- K2: S[m][n] = xn_row_m . tok_n  (m in [0,816), n in [0,768)) ----------
__global__ __launch_bounds__(256) void k2_gemm(const float* __restrict__ xn,
                                               float* __restrict__ S) {
  __shared__ float As[16][17];
  __shared__ float Bs[16][17];
  int m0 = blockIdx.y * 16, n0 = blockIdx.x * 16;
  int tx = threadIdx.x, ty = threadIdx.y;
  const float* tok = xn + Bn * Dn;
  float acc = 0.f;
  for (int k0 = 0; k0 < Dn; k0 += 16) {
    As[ty][tx] = xn[(m0 + ty) * Dn + k0 + tx];
    Bs[ty][tx] = tok[(n0 + ty) * Dn + k0 + tx];
    __syncthreads();
    #pragma unroll
    for (int kk = 0; kk < 16; ++kk) acc += As[ty][kk] * Bs[tx][kk];
    __syncthreads();
  }
  S[(m0 + ty) * Mn + (n0 + tx)] = acc;   // T = 1.0 -> no scale
}

// ---------- K3: per-anchor i: log_denom, LSE_a, la/sm_a tables (fp64) ----------
__global__ __launch_bounds__(256) void k3_setup(const float* __restrict__ S,
                                                const int* __restrict__ label,
                                                double* __restrict__ ld,
                                                double* __restrict__ la,
                                                double* __restrict__ sma,
                                                double* __restrict__ acc) {
  __shared__ double red[8];
  __shared__ int lab[Bn];
  int i = blockIdx.x, tid = threadIdx.x;
  if (tid < Bn) lab[tid] = label[tid];
  __syncthreads();
  int li = lab[i];
  const float* sa = S + i * Mn;          // s_anc row i

  // log_denom = logsumexp over neg k of s_anc
  double m1 = -1e300;
  for (int k = tid; k < Mn; k += 256)
    if (lab[k >> 4] != li) m1 = fmax(m1, (double)sa[k]);
  m1 = blockReduceMax(m1, red);
  double s1 = 0.0;
  for (int k = tid; k < Mn; k += 256)
    if (lab[k >> 4] != li) s1 += exp((double)sa[k] - m1);
  s1 = blockReduceSum(s1, red);
  double ldi = m1 + log(s1);

  // LSE_a = logsumexp over neg k of a_unify (= exp(s_anc - ld))
  double m2 = -1e300;
  for (int k = tid; k < Mn; k += 256)
    if (lab[k >> 4] != li) m2 = fmax(m2, exp((double)sa[k] - ldi));
  m2 = blockReduceMax(m2, red);
  double s2 = 0.0;
  for (int k = tid; k < Mn; k += 256)
    if (lab[k >> 4] != li) s2 += exp(exp((double)sa[k] - ldi) - m2);
  s2 = blockReduceSum(s2, red);
  double lsea = m2 + log(s2);

  for (int k = tid; k < Mn; k += 256) {
    bool neg = (lab[k >> 4] != li);
    double au = neg ? exp((double)sa[k] - ldi) : 0.0;
    double lak = neg ? (au - lsea) : (NEGV - lsea);
    la[i * Mn + k] = lak;
    sma[i * Mn + k] = neg ? exp(lak) : 0.0;
  }
  if (tid == 0) { ld[i] = ldi; acc[i] = 0.0; }
}

// ---------- K4: per (i, positive j): symmetric KL over neg k ----------
__global__ __launch_bounds__(256) void k4_main(const float* __restrict__ S,
                                               const int* __restrict__ label,
                                               const double* __restrict__ ld,
                                               const double* __restrict__ la,
                                               const double* __restrict__ sma,
                                               double* __restrict__ acc) {
  int i = blockIdx.y, j = blockIdx.x;
  int li = label[i];
  if (label[j >> 4] != li) return;       // only positive j contribute (row weight)

  __shared__ int lab[Bn];
  __shared__ double eds[Mn];             // e_k = exp(s_tok[j,k] - ld_i)
  __shared__ double wds[Mn];             // exp(e_k - m3)
  __shared__ double red[8];
  int tid = threadIdx.x;
  if (tid < Bn) lab[tid] = label[tid];
  __syncthreads();

  const float* st = S + (Bn + j) * Mn;   // s_tok row j
  double ldi = ld[i];

  double m3 = -1e300;
  for (int k = tid; k < Mn; k += 256) {
    bool neg = (lab[k >> 4] != li);
    double e = neg ? exp((double)st[k] - ldi) : -1e300;
    eds[k] = e;
    if (neg) m3 = fmax(m3, e);
  }
  m3 = blockReduceMax(m3, red);

  double s3 = 0.0;
  for (int k = tid; k < Mn; k += 256) {
    bool neg = (lab[k >> 4] != li);
    double w = neg ? exp(eds[k] - m3) : 0.0;
    wds[k] = w;
    s3 += w;
  }
  s3 = blockReduceSum(s3, red);
  double lsep = m3 + log(s3);
  double inv_s3 = 1.0 / s3;

  // 0.5*(kl1+kl2) = 0.5 * sum_negk (sm_p - sm_a) * (log_p - log_a)
  double t = 0.0;
  for (int k = tid; k < Mn; k += 256) {
    if (lab[k >> 4] != li) {
      double lp  = eds[k] - lsep;
      double smp = wds[k] * inv_s3;      // == exp(lp) to ~1 ulp
      double d1 = smp - sma[i * Mn + k];
      double d2 = lp  - la[i * Mn + k];
      t += d1 * d2;
    }
  }
  t = blockReduceSum(t, red);
  if (tid == 0) atomicAdd(&acc[i], 0.5 * t);
}

// ---------- K5: loss = mean_i acc[i] / P_i ----------
__global__ __launch_bounds__(64) void k5_final(const double* __restrict__ acc,
                                               const int* __restrict__ label,
                                               float* __restrict__ out) {
  int tid = threadIdx.x;
  double v = 0.0;
  if (tid < Bn) {
    int li = label[tid];
    int cnt = 0;
    for (int b = 0; b < Bn; ++b) cnt += (label[b] == li) ? 1 : 0;
    double P = 16.0 * (double)cnt;       // (L-1) * matching batches
    v = acc[tid] / P;
  }
  #pragma unroll
  for (int o = 32; o > 0; o >>= 1) v += __shfl_down(v, o, 64);
  if (tid == 0) out[0] = (float)(v / (double)Bn);
}

extern "C" void kernel_launch(void* const* d_in, const int* in_sizes, int n_in,
                              void* d_out, int out_size, void* d_ws, size_t ws_size,
                              hipStream_t stream) {
  const float* x   = (const float*)d_in[0];
  const int* label = (const int*)d_in[1];
  float* out = (float*)d_out;

  char* ws = (char*)d_ws;
  size_t off = 0;
  auto alloc = [&](size_t bytes) -> void* {
    void* p = ws + off;
    off = (off + bytes + 255) & ~(size_t)255;
    return p;
  };
  float*  xn  = (float*) alloc((size_t)ROWS * Dn * sizeof(float));
  float*  S   = (float*) alloc((size_t)ROWS * Mn * sizeof(float));
  double* ld  = (double*)alloc((size_t)Bn * sizeof(double));
  double* la  = (double*)alloc((size_t)Bn * Mn * sizeof(double));
  double* sma = (double*)alloc((size_t)Bn * Mn * sizeof(double));
  double* acc = (double*)alloc((size_t)Bn * sizeof(double));

  k1_normalize<<<ROWS, 256, 0, stream>>>(x, xn);
  k2_gemm<<<dim3(Mn / 16, ROWS / 16), dim3(16, 16), 0, stream>>>(xn, S);
  k3_setup<<<Bn, 256, 0, stream>>>(S, label, ld, la, sma, acc);
  k4_main<<<dim3(Mn, Bn), 256, 0, stream>>>(S, label, ld, la, sma, acc);
  k5_final<<<1, 64, 0, stream>>>(acc, label, out);
}

// Round 2
// 114.258 us; speedup vs baseline: 1.1153x; 1.1153x over previous
//
#include <hip/hip_runtime.h>
#include <math.h>

#define Bn 48
#define Ln 17
#define Dn 256
#define Mn 768        // Bn*(Ln-1)
#define ROWS 816      // 48 anchors + 768 toks

// exp(e) for e in [0, ~0.02]; rel err < 1e-14 (e^6/720 at e=0.013 ~ 7e-15)
static __device__ __forceinline__ double pexp(double e) {
  return 1.0 + e*(1.0 + e*(0.5 + e*((1.0/6.0) + e*((1.0/24.0) + e*(1.0/120.0)))));
}

static __device__ __forceinline__ double blockReduceSum256(double v, double* red) {
  #pragma unroll
  for (int o = 32; o > 0; o >>= 1) v += __shfl_down(v, o, 64);
  int lane = threadIdx.x & 63, wid = threadIdx.x >> 6;
  __syncthreads();
  if (lane == 0) red[wid] = v;
  __syncthreads();
  return red[0] + red[1] + red[2] + red[3];
}

// ---------- K1: normalize rows; layout [anchors(48); toks(768)] fp32 ----------
__global__ __launch_bounds__(256) void k1_normalize(const float* __restrict__ x,
                                                    float* __restrict__ xn) {
  __shared__ double red[4];
  int row = blockIdx.x;            // 0..815 over (b,l)
  int b = row / Ln, l = row % Ln;
  int tid = threadIdx.x;
  float v = x[row * Dn + tid];
  double ss = blockReduceSum256((double)v * (double)v, red);
  double denom = fmax(sqrt(ss), 1e-12);
  float o = (float)((double)v / denom);
  int orow = (l == 0) ? b : (Bn + b * (Ln - 1) + (l - 1));
  xn[orow * Dn + tid] = o;
}

// ---------- K2: S = xn @ toks^T; epilogue writes exp(S) ----------
// rows <48 -> EA (anchor exp table), rows >=48 -> E (token exp table)
__global__ __launch_bounds__(256) void k2_gemm(const float* __restrict__ xn,
                                               double* __restrict__ EA,
                                               double* __restrict__ E) {
  __shared__ float As[16][17];
  __shared__ float Bs[16][17];
  int m0 = blockIdx.y * 16, n0 = blockIdx.x * 16;
  int tx = threadIdx.x, ty = threadIdx.y;
  const float* tok = xn + Bn * Dn;
  float acc = 0.f;
  for (int k0 = 0; k0 < Dn; k0 += 16) {
    As[ty][tx] = xn[(m0 + ty) * Dn + k0 + tx];
    Bs[ty][tx] = tok[(n0 + ty) * Dn + k0 + tx];
    __syncthreads();
    #pragma unroll
    for (int kk = 0; kk < 16; ++kk) acc += As[ty][kk] * Bs[tx][kk];
    __syncthreads();
  }
  int m = m0 + ty, n = n0 + tx;
  double ev = exp((double)acc);          // T = 1.0
  if (m < Bn) EA[m * Mn + n] = ev;
  else        E[(m - Bn) * Mn + n] = ev;
}

// ---------- K3: per-anchor i: ci = 1/sum_neg(EA); au, sma tables; Ev ----------
__global__ __launch_bounds__(256) void k3_setup(const double* __restrict__ EA,
                                                const int* __restrict__ label,
                                                double* __restrict__ sma,
                                                double* __restrict__ au,
                                                double* __restrict__ ci_g,
                                                double* __restrict__ Ev_g,
                                                double* __restrict__ acc) {
  __shared__ double red[4];
  __shared__ int lab[Bn];
  int i = blockIdx.x, tid = threadIdx.x;
  if (tid < Bn) lab[tid] = label[tid];
  __syncthreads();
  int li = lab[i];
  const double* ea = EA + i * Mn;

  double s1 = 0.0;
  for (int k = tid; k < Mn; k += 256)
    if (lab[k >> 4] != li) s1 += ea[k];
  s1 = blockReduceSum256(s1, red);
  double ci = 1.0 / s1;                  // exp(-log_denom)

  double s2 = 0.0;
  for (int k = tid; k < Mn; k += 256)
    if (lab[k >> 4] != li) s2 += pexp(ea[k] * ci);
  s2 = blockReduceSum256(s2, red);
  double inv_s2 = 1.0 / s2;

  double ev = 0.0;
  for (int k = tid; k < Mn; k += 256) {
    bool neg = (lab[k >> 4] != li);
    double a  = neg ? ea[k] * ci : 0.0;          // a_unify (2nd-softmax logit)
    double sm = neg ? pexp(a) * inv_s2 : 0.0;    // sm_a (sums to 1 over neg)
    sma[i * Mn + k] = sm;
    au [i * Mn + k] = a;                          // log_a + const (shift cancels)
    ev += sm * a;
  }
  ev = blockReduceSum256(ev, red);
  if (tid == 0) { ci_g[i] = ci; Ev_g[i] = ev; acc[i] = 0.0; }
}

// ---------- K4: per (i, batch bj): 16 j's across 4 waves; single pass ----------
// t(i,j) = (A - Bv)/C - D + Ev_i  with  A=sum w*e, Bv=sum w*au, C=sum w, D=sum sma*e
__global__ __launch_bounds__(256) void k4_main(const double* __restrict__ E,
                                               const int* __restrict__ label,
                                               const double* __restrict__ sma,
                                               const double* __restrict__ au,
                                               const double* __restrict__ ci_g,
                                               const double* __restrict__ Ev_g,
                                               double* __restrict__ acc) {
  int bj = blockIdx.x, i = blockIdx.y;
  int li = label[i];
  if (label[bj] != li) return;           // only same-label batches contribute

  __shared__ int lab[Bn];
  __shared__ double ssma[Mn];
  __shared__ double sau[Mn];
  int tid = threadIdx.x;
  if (tid < Bn) lab[tid] = label[tid];
  for (int k = tid; k < Mn; k += 256) {
    ssma[k] = sma[i * Mn + k];
    sau [k] = au [i * Mn + k];
  }
  __syncthreads();

  double ci = ci_g[i], Evi = Ev_g[i];
  int lane = tid & 63, wave = tid >> 6;

  double tsum = 0.0;
  #pragma unroll
  for (int jj = 0; jj < 4; ++jj) {
    int j = bj * 16 + wave * 4 + jj;
    const double* Ej = E + j * Mn;
    double A = 0.0, Bv = 0.0, C = 0.0, D = 0.0;
    for (int k = lane; k < Mn; k += 64) {
      if (lab[k >> 4] != li) {
        double e = ci * Ej[k];           // p_unify (2nd-softmax logit)
        double w = pexp(e);
        A += w * e; Bv += w * sau[k]; C += w; D += ssma[k] * e;
      }
    }
    #pragma unroll
    for (int o = 32; o > 0; o >>= 1) {
      A  += __shfl_xor(A,  o, 64);
      Bv += __shfl_xor(Bv, o, 64);
      C  += __shfl_xor(C,  o, 64);
      D  += __shfl_xor(D,  o, 64);
    }
    tsum += (A - Bv) / C - D + Evi;
  }
  if (lane == 0) atomicAdd(&acc[i], 0.5 * tsum);
}

// ---------- K5: loss = mean_i acc[i] / P_i ----------
__global__ __launch_bounds__(64) void k5_final(const double* __restrict__ acc,
                                               const int* __restrict__ label,
                                               float* __restrict__ out) {
  int tid = threadIdx.x;
  double v = 0.0;
  if (tid < Bn) {
    int li = label[tid];
    int cnt = 0;
    for (int b = 0; b < Bn; ++b) cnt += (label[b] == li) ? 1 : 0;
    double P = 16.0 * (double)cnt;
    v = acc[tid] / P;
  }
  #pragma unroll
  for (int o = 32; o > 0; o >>= 1) v += __shfl_down(v, o, 64);
  if (tid == 0) out[0] = (float)(v / (double)Bn);
}

extern "C" void kernel_launch(void* const* d_in, const int* in_sizes, int n_in,
                              void* d_out, int out_size, void* d_ws, size_t ws_size,
                              hipStream_t stream) {
  const float* x   = (const float*)d_in[0];
  const int* label = (const int*)d_in[1];
  float* out = (float*)d_out;

  char* ws = (char*)d_ws;
  size_t off = 0;
  auto alloc = [&](size_t bytes) -> void* {
    void* p = ws + off;
    off = (off + bytes + 255) & ~(size_t)255;
    return p;
  };
  float*  xn  = (float*) alloc((size_t)ROWS * Dn * sizeof(float));
  double* EA  = (double*)alloc((size_t)Bn * Mn * sizeof(double));
  double* E   = (double*)alloc((size_t)Mn * Mn * sizeof(double));
  double* sma = (double*)alloc((size_t)Bn * Mn * sizeof(double));
  double* au  = (double*)alloc((size_t)Bn * Mn * sizeof(double));
  double* ci  = (double*)alloc((size_t)Bn * sizeof(double));
  double* Ev  = (double*)alloc((size_t)Bn * sizeof(double));
  double* acc = (double*)alloc((size_t)Bn * sizeof(double));

  k1_normalize<<<ROWS, 256, 0, stream>>>(x, xn);
  k2_gemm<<<dim3(Mn / 16, ROWS / 16), dim3(16, 16), 0, stream>>>(xn, EA, E);
  k3_setup<<<Bn, 256, 0, stream>>>(EA, label, sma, au, ci, Ev, acc);
  k4_main<<<dim3(Bn, Bn), 256, 0, stream>>>(E, label, sma, au, ci, Ev, acc);
  k5_final<<<1, 64, 0, stream>>>(acc, label, out);
}